// Round 14
// baseline (69.748 us; speedup 1.0000x reference)
//
#include <hip/hip_runtime.h>
#include <hip/hip_bf16.h>
#include <math.h>

#define LL 1024
#define DD 512
#define HH 256

// ws layout (floats):
//   pC : [4][512][1024] f32 @ 0        gemm K-partials (n = mat*256+h)  (8 MB)
//   O  : [512][1024] bf16  @ 2097152   rows 0:256 = t(+b1), 256:512 = u (1 MB)

__device__ __forceinline__ ushort f2bf(float f) {
  __hip_bfloat16 h = __float2bfloat16(f);
  return *reinterpret_cast<ushort*>(&h);
}
__device__ __forceinline__ float bf_lo(unsigned int u) { return __uint_as_float(u << 16); }
__device__ __forceinline__ float bf_hi(unsigned int u) { return __uint_as_float(u & 0xffff0000u); }

// ---------------------------------------------------------------------------
// Kernel 1 (R11-proven, verbatim): GEMM partials. Tile 128i x 64n x 128k,
// 512 thr, 4i x 4n per thread, grid (8,8,4)=256. Dbuf BK=32.
// ---------------------------------------------------------------------------
__global__ __launch_bounds__(512) void sp_gemm(
    const float* __restrict__ S, const float* __restrict__ W1,
    float* __restrict__ pC) {
  __shared__ float Sl[2][128][36];   // 36.9 KB
  __shared__ float Wl[2][64][36];    // 18.4 KB

  const int tid = threadIdx.x;
  const int tx  = tid & 15;
  const int ty  = tid >> 4;
  const int i0  = blockIdx.x * 128;
  const int n0  = blockIdx.y * 64;
  const int kz  = blockIdx.z * 128;

  const int srow = tid >> 3;
  const int ssl  = tid & 7;
  const int wn   = n0 + srow;
  const float* s0 = S + (size_t)(i0 + srow) * DD + kz + 4 * ssl;
  const float* s1 = S + (size_t)(i0 + 64 + srow) * DD + kz + 4 * ssl;
  const float* w0 = W1 + (size_t)(wn & 255) * (2 * DD) + (wn >> 8) * DD + kz + 4 * ssl;

  float4 sA, sB, wA;
  auto ld = [&](int c) {
    sA = *(const float4*)(s0 + 32 * c);
    sB = *(const float4*)(s1 + 32 * c);
    wA = *(const float4*)(w0 + 32 * c);
  };
  auto st = [&](int b) {
    *(float4*)&Sl[b][srow][4 * ssl]      = sA;
    *(float4*)&Sl[b][64 + srow][4 * ssl] = sB;
    *(float4*)&Wl[b][srow][4 * ssl]      = wA;
  };

  float acc[4][4] = {{0.f}};

  ld(0); st(0); __syncthreads();

  for (int c = 0; c < 4; ++c) {
    const int cur = c & 1;
    if (c < 3) ld(c + 1);
    #pragma unroll 2
    for (int k4 = 0; k4 < 8; ++k4) {
      float4 wf[4], sf[4];
      #pragma unroll
      for (int b = 0; b < 4; ++b) wf[b] = *(const float4*)&Wl[cur][tx + 16 * b][4 * k4];
      #pragma unroll
      for (int a = 0; a < 4; ++a) sf[a] = *(const float4*)&Sl[cur][4 * ty + a][4 * k4];
      #pragma unroll
      for (int a = 0; a < 4; ++a) {
        #pragma unroll
        for (int b = 0; b < 4; ++b) {
          acc[a][b] += sf[a].x * wf[b].x + sf[a].y * wf[b].y +
                       sf[a].z * wf[b].z + sf[a].w * wf[b].w;
        }
      }
    }
    if (c < 3) st(cur ^ 1);
    __syncthreads();
  }

  float* base = pC + (size_t)blockIdx.z * (512 * LL);
  #pragma unroll
  for (int b = 0; b < 4; ++b) {
    const int n = n0 + tx + 16 * b;
    *(float4*)(base + (size_t)n * LL + i0 + 4 * ty) =
        make_float4(acc[0][b], acc[1][b], acc[2][b], acc[3][b]);
  }
}

// ---------------------------------------------------------------------------
// Kernel 2: reduce 4 K-partials + fold b1 -> O bf16 [512][1024].
// grid 512 x 256 thr, 1 float4-group (-> ushort4) per thread. ~1.5 us.
// ---------------------------------------------------------------------------
__global__ __launch_bounds__(256) void sp_reduce(
    const float* __restrict__ pC, const float* __restrict__ b1,
    ushort* __restrict__ O) {
  const int m = blockIdx.x * 256 + threadIdx.x;   // 0..131071 f4-groups
  const int n = m >> 8;
  const int NW = 512 * 256;                       // f4 per z-partial
  const float4* p = (const float4*)pC + m;
  float4 a  = p[0];
  const float4 v1 = p[NW], v2 = p[2 * NW], v3 = p[3 * NW];
  a.x += v1.x + v2.x + v3.x;
  a.y += v1.y + v2.y + v3.y;
  a.z += v1.z + v2.z + v3.z;
  a.w += v1.w + v2.w + v3.w;
  if (n < 256) {
    const float bb = b1[n];
    a.x += bb; a.y += bb; a.z += bb; a.w += bb;
  }
  ushort4 o;
  o.x = f2bf(a.x); o.y = f2bf(a.y); o.z = f2bf(a.z); o.w = f2bf(a.w);
  *(ushort4*)(O + 4 * (size_t)m) = o;
}

// ---------------------------------------------------------------------------
// Kernel 3: FUSED pairwise + symmetrize + sigmoid. Triangular grid: 528
// blocks, block t -> (bY<=bX); R-rows i0=32*bY, C-cols j0=32*bX. Stages 4
// bf16 panels (TR,UC for tile P(i,j); TC,UR for tile P(j,i)), 74 KB LDS ->
// 2 blocks/CU = 2 waves/SIMD. Each thread: acc1[2][2] at (r,c) and
// acc2[2][2] at transposed coords (c,r), so out = sig(0.25(P1+P2^T)+b2)
// is fully in-register. relu(x)=(x+|x|)/2 via rank-1 A/B + |.| inner.
// Inner/h: 4 ds_read_b32 (conflict-free) + 8 unpack + 16 add/fma.
// Diagonal blocks write the same values twice (benign).
// ---------------------------------------------------------------------------
__global__ __launch_bounds__(256, 2) void sp_fused(
    const ushort* __restrict__ O, const float* __restrict__ W2,
    const float* __restrict__ b2, float* __restrict__ out) {
  __shared__ ushort TR[256][36];   // t panel, R rows (i)
  __shared__ ushort UC[256][36];   // u panel, C cols (j)
  __shared__ ushort TC[256][36];   // t panel, C cols (j)
  __shared__ ushort UR[256][36];   // u panel, R rows (i)
  __shared__ float PR[2][128];
  __shared__ float AB[128];        // [0:32)=A_R [32:64)=B_C [64:96)=A_C [96:128)=B_R

  const int tid = threadIdx.x;
  const int tx  = tid & 15;        // c = 2tx + b
  const int ty  = tid >> 4;        // r = 2ty + a

  // triangular decode: t -> bX (0..31), bY (0..bX)
  int t = blockIdx.x;
  int bX = (int)((sqrtf(8.0f * t + 1.0f) - 1.0f) * 0.5f);
  while ((bX + 1) * (bX + 2) / 2 <= t) ++bX;
  while (bX * (bX + 1) / 2 > t) --bX;
  const int bY = t - bX * (bX + 1) / 2;
  const int i0 = bY * 32;          // row range R
  const int j0 = bX * 32;          // col range C

  // stage 4 panels (16B global loads -> 2x8B LDS writes, 8B-aligned rows)
  #pragma unroll
  for (int q = 0; q < 4; ++q) {
    const int m   = q * 256 + tid;   // 0..1023
    const int row = m >> 2;          // h
    const int sl  = m & 3;           // 8-ushort segment
    const uint4 a = *(const uint4*)(O + (size_t)row * LL + i0 + 8 * sl);
    const uint4 b = *(const uint4*)(O + (size_t)(HH + row) * LL + j0 + 8 * sl);
    const uint4 c = *(const uint4*)(O + (size_t)row * LL + j0 + 8 * sl);
    const uint4 d = *(const uint4*)(O + (size_t)(HH + row) * LL + i0 + 8 * sl);
    *(uint2*)&TR[row][8 * sl]     = make_uint2(a.x, a.y);
    *(uint2*)&TR[row][8 * sl + 4] = make_uint2(a.z, a.w);
    *(uint2*)&UC[row][8 * sl]     = make_uint2(b.x, b.y);
    *(uint2*)&UC[row][8 * sl + 4] = make_uint2(b.z, b.w);
    *(uint2*)&TC[row][8 * sl]     = make_uint2(c.x, c.y);
    *(uint2*)&TC[row][8 * sl + 4] = make_uint2(c.z, c.w);
    *(uint2*)&UR[row][8 * sl]     = make_uint2(d.x, d.y);
    *(uint2*)&UR[row][8 * sl + 4] = make_uint2(d.z, d.w);
  }
  __syncthreads();

  // rank-1 prologue: 128 (panel,col) combos x 2 h-slices
  {
    const int x = tid & 127, hs = tid >> 7;
    const int p = x >> 5, col = x & 31;
    const ushort* pan = (p == 0) ? &TR[0][0] : (p == 1) ? &UC[0][0]
                      : (p == 2) ? &TC[0][0] : &UR[0][0];
    float s = 0.f;
    #pragma unroll 8
    for (int n = 0; n < 128; ++n) {
      const int h = hs * 128 + n;
      s = fmaf(__uint_as_float(((unsigned int)pan[h * 36 + col]) << 16), W2[h], s);
    }
    PR[hs][x] = s;
  }
  __syncthreads();
  if (tid < 128) AB[tid] = PR[0][tid] + PR[1][tid];
  __syncthreads();

  float acc1[2][2] = {{0.f}};   // P(i,j) tile, [a][b] at (2ty+a, 2tx+b)
  float acc2[2][2] = {{0.f}};   // P(j,i) tile, [b][a] at (2tx+b, 2ty+a)

  #pragma unroll 4
  for (int h = 0; h < HH; ++h) {
    const float w = W2[h];
    const unsigned int tr = *(const unsigned int*)&TR[h][2 * ty];
    const unsigned int uc = *(const unsigned int*)&UC[h][2 * tx];
    const unsigned int tc = *(const unsigned int*)&TC[h][2 * tx];
    const unsigned int ur = *(const unsigned int*)&UR[h][2 * ty];
    const float t0 = bf_lo(tr), t1 = bf_hi(tr);
    const float u0 = bf_lo(uc), u1 = bf_hi(uc);
    const float c0 = bf_lo(tc), c1 = bf_hi(tc);
    const float r0 = bf_lo(ur), r1 = bf_hi(ur);
    acc1[0][0] = fmaf(fabsf(t0 + u0), w, acc1[0][0]);
    acc1[0][1] = fmaf(fabsf(t0 + u1), w, acc1[0][1]);
    acc1[1][0] = fmaf(fabsf(t1 + u0), w, acc1[1][0]);
    acc1[1][1] = fmaf(fabsf(t1 + u1), w, acc1[1][1]);
    acc2[0][0] = fmaf(fabsf(c0 + r0), w, acc2[0][0]);
    acc2[0][1] = fmaf(fabsf(c0 + r1), w, acc2[0][1]);
    acc2[1][0] = fmaf(fabsf(c1 + r0), w, acc2[1][0]);
    acc2[1][1] = fmaf(fabsf(c1 + r1), w, acc2[1][1]);
  }

  const float bb = b2[0];
  float v[2][2];
  #pragma unroll
  for (int a = 0; a < 2; ++a) {
    #pragma unroll
    for (int b = 0; b < 2; ++b) {
      const float P1 = acc1[a][b] + AB[2 * ty + a] + AB[32 + 2 * tx + b];
      const float P2 = acc2[b][a] + AB[64 + 2 * tx + b] + AB[96 + 2 * ty + a];
      const float x = 0.25f * (P1 + P2) + bb;
      v[a][b] = 1.f / (1.f + expf(-x));
    }
  }

  // direct tile: rows i0+2ty+a, cols j0+2tx
  #pragma unroll
  for (int a = 0; a < 2; ++a) {
    *(float2*)(out + (size_t)(i0 + 2 * ty + a) * LL + j0 + 2 * tx) =
        make_float2(v[a][0], v[a][1]);
  }
  // transposed tile: rows j0+2tx+b, cols i0+2ty (same values, L2 merges)
  #pragma unroll
  for (int b = 0; b < 2; ++b) {
    *(float2*)(out + (size_t)(j0 + 2 * tx + b) * LL + i0 + 2 * ty) =
        make_float2(v[0][b], v[1][b]);
  }
}

// ---------------------------------------------------------------------------
extern "C" void kernel_launch(void* const* d_in, const int* in_sizes, int n_in,
                              void* d_out, int out_size, void* d_ws, size_t ws_size,
                              hipStream_t stream) {
  const float* S  = (const float*)d_in[0];   // [L, D]
  const float* W1 = (const float*)d_in[1];   // [H, 2D]
  const float* b1 = (const float*)d_in[2];   // [H]
  const float* W2 = (const float*)d_in[3];   // [1, H]
  const float* b2 = (const float*)d_in[4];   // [1]
  float* out = (float*)d_out;

  float* ws = (float*)d_ws;
  float* pC = ws;                            // [4][512][1024] f32
  ushort* O = (ushort*)(ws + 4 * 512 * LL);  // [512][1024] bf16

  hipLaunchKernelGGL(sp_gemm, dim3(8, 8, 4), dim3(512), 0, stream,
                     S, W1, pC);
  hipLaunchKernelGGL(sp_reduce, dim3(512), dim3(256), 0, stream,
                     pC, b1, O);
  hipLaunchKernelGGL(sp_fused, dim3(528), dim3(256), 0, stream,
                     O, W2, b2, out);
}

// Round 15
// 50.112 us; speedup vs baseline: 1.3918x; 1.3918x over previous
//
#include <hip/hip_runtime.h>
#include <hip/hip_bf16.h>
#include <math.h>

#define LL 1024
#define DD 512
#define HH 256

// ws layout (floats):
//   pC : [4][512][1024] f32 @ 0         gemm K-partials (n = mat*256+h) (8 MB)
//   O  : [512][1024] bf16  @ 2097152    rows 0:256 = t(+b1), 256:512 = u (1 MB)
//   pz : [2][1024][1024] f32 @ 2359296  pairwise h-half partials        (8 MB)

__device__ __forceinline__ ushort f2bf(float f) {
  __hip_bfloat16 h = __float2bfloat16(f);
  return *reinterpret_cast<ushort*>(&h);
}
__device__ __forceinline__ float bf_lo(unsigned int u) { return __uint_as_float(u << 16); }
__device__ __forceinline__ float bf_hi(unsigned int u) { return __uint_as_float(u & 0xffff0000u); }

// ---------------------------------------------------------------------------
// Kernel 1 (R11-proven, verbatim): GEMM partials. Tile 128i x 64n x 128k,
// 512 thr, 4i x 4n per thread, grid (8,8,4)=256. Dbuf BK=32.
// ---------------------------------------------------------------------------
__global__ __launch_bounds__(512) void sp_gemm(
    const float* __restrict__ S, const float* __restrict__ W1,
    float* __restrict__ pC) {
  __shared__ float Sl[2][128][36];   // 36.9 KB
  __shared__ float Wl[2][64][36];    // 18.4 KB

  const int tid = threadIdx.x;
  const int tx  = tid & 15;
  const int ty  = tid >> 4;
  const int i0  = blockIdx.x * 128;
  const int n0  = blockIdx.y * 64;
  const int kz  = blockIdx.z * 128;

  const int srow = tid >> 3;
  const int ssl  = tid & 7;
  const int wn   = n0 + srow;
  const float* s0 = S + (size_t)(i0 + srow) * DD + kz + 4 * ssl;
  const float* s1 = S + (size_t)(i0 + 64 + srow) * DD + kz + 4 * ssl;
  const float* w0 = W1 + (size_t)(wn & 255) * (2 * DD) + (wn >> 8) * DD + kz + 4 * ssl;

  float4 sA, sB, wA;
  auto ld = [&](int c) {
    sA = *(const float4*)(s0 + 32 * c);
    sB = *(const float4*)(s1 + 32 * c);
    wA = *(const float4*)(w0 + 32 * c);
  };
  auto st = [&](int b) {
    *(float4*)&Sl[b][srow][4 * ssl]      = sA;
    *(float4*)&Sl[b][64 + srow][4 * ssl] = sB;
    *(float4*)&Wl[b][srow][4 * ssl]      = wA;
  };

  float acc[4][4] = {{0.f}};

  ld(0); st(0); __syncthreads();

  for (int c = 0; c < 4; ++c) {
    const int cur = c & 1;
    if (c < 3) ld(c + 1);
    #pragma unroll 2
    for (int k4 = 0; k4 < 8; ++k4) {
      float4 wf[4], sf[4];
      #pragma unroll
      for (int b = 0; b < 4; ++b) wf[b] = *(const float4*)&Wl[cur][tx + 16 * b][4 * k4];
      #pragma unroll
      for (int a = 0; a < 4; ++a) sf[a] = *(const float4*)&Sl[cur][4 * ty + a][4 * k4];
      #pragma unroll
      for (int a = 0; a < 4; ++a) {
        #pragma unroll
        for (int b = 0; b < 4; ++b) {
          acc[a][b] += sf[a].x * wf[b].x + sf[a].y * wf[b].y +
                       sf[a].z * wf[b].z + sf[a].w * wf[b].w;
        }
      }
    }
    if (c < 3) st(cur ^ 1);
    __syncthreads();
  }

  float* base = pC + (size_t)blockIdx.z * (512 * LL);
  #pragma unroll
  for (int b = 0; b < 4; ++b) {
    const int n = n0 + tx + 16 * b;
    *(float4*)(base + (size_t)n * LL + i0 + 4 * ty) =
        make_float4(acc[0][b], acc[1][b], acc[2][b], acc[3][b]);
  }
}

// ---------------------------------------------------------------------------
// Kernel 2 (R14-proven): reduce 4 K-partials + fold b1 -> O bf16 [512][1024].
// grid 512 x 256 thr. ~2 us.
// ---------------------------------------------------------------------------
__global__ __launch_bounds__(256) void sp_reduce(
    const float* __restrict__ pC, const float* __restrict__ b1,
    ushort* __restrict__ O) {
  const int m = blockIdx.x * 256 + threadIdx.x;   // 0..131071 f4-groups
  const int n = m >> 8;
  const int NW = 512 * 256;                       // f4 per z-partial
  const float4* p = (const float4*)pC + m;
  float4 a  = p[0];
  const float4 v1 = p[NW], v2 = p[2 * NW], v3 = p[3 * NW];
  a.x += v1.x + v2.x + v3.x;
  a.y += v1.y + v2.y + v3.y;
  a.z += v1.z + v2.z + v3.z;
  a.w += v1.w + v2.w + v3.w;
  if (n < 256) {
    const float bb = b1[n];
    a.x += bb; a.y += bb; a.z += bb; a.w += bb;
  }
  ushort4 o;
  o.x = f2bf(a.x); o.y = f2bf(a.y); o.z = f2bf(a.z); o.w = f2bf(a.w);
  *(ushort4*)(O + 4 * (size_t)m) = o;
}

// ---------------------------------------------------------------------------
// Kernel 3 (R13-proven shape): pairwise, bf16 panels staged from the 1 MB
// L2/L3-resident O (NOT the 8 MB pC -- R11's hidden 128 MB re-read).
// Block z covers h in [128z,128z+128): pz[z](i,j) = A_z(i)+B_z(j)+sum|t+u|w.
// 256 thr, tile 64x64, 4i x 4j. Panels ushort[128][72] x2 = 36.9 KB
// -> 4 blocks/CU = 16 waves/CU = 4 waves/SIMD, grid (16,16,2)=512.
// ---------------------------------------------------------------------------
__global__ __launch_bounds__(256, 4) void sp_pairwise(
    const ushort* __restrict__ O, const float* __restrict__ W2,
    float* __restrict__ pz) {
  __shared__ ushort Tl[128][72];   // 18.4 KB
  __shared__ ushort Ul[128][72];   // 18.4 KB
  __shared__ float PR[2][128];
  __shared__ float As[64], Bs[64];

  const int tid = threadIdx.x;
  const int tx  = tid & 15;       // j = j0 + 4tx + b
  const int ty  = tid >> 4;       // i = i0 + 4ty + a, ty 0..15
  const int j0  = blockIdx.x * 64;
  const int i0  = blockIdx.y * 64;
  const int hz  = blockIdx.z * 128;

  #pragma unroll
  for (int q = 0; q < 8; ++q) {
    const int m = q * 256 + tid;           // 0..2047
    const int hh = m >> 4;                 // 0..127
    const int g8 = (m & 15) * 4;           // ushort col
    *(ushort4*)&Tl[hh][g8] =
        *(const ushort4*)(O + (size_t)(hz + hh) * LL + i0 + g8);
    *(ushort4*)&Ul[hh][g8] =
        *(const ushort4*)(O + (size_t)(HH + hz + hh) * LL + j0 + g8);
  }
  __syncthreads();

  // rank-1 prologue over this h-half
  {
    const int x = tid & 127, hs = tid >> 7;    // hs 0..1
    const ushort* pan = (x < 64) ? &Tl[0][x] : &Ul[0][x - 64];
    float p = 0.f;
    #pragma unroll 8
    for (int n = 0; n < 64; ++n) {
      const int hh = hs * 64 + n;
      const float v = __uint_as_float(((unsigned int)pan[hh * 72]) << 16);
      p = fmaf(v, W2[hz + hh], p);
    }
    PR[hs][x] = p;
  }
  __syncthreads();
  if (tid < 128) {
    const float s = PR[0][tid] + PR[1][tid];
    if (tid < 64) As[tid] = s; else Bs[tid - 64] = s;
  }
  __syncthreads();

  float acc[4][4] = {{0.f}};

  #pragma unroll 4
  for (int hh = 0; hh < 128; ++hh) {
    const uint2 tr = *(const uint2*)&Tl[hh][4 * ty];
    const uint2 ur = *(const uint2*)&Ul[hh][4 * tx];
    const float w = W2[hz + hh];
    const float tv[4] = {bf_lo(tr.x), bf_hi(tr.x), bf_lo(tr.y), bf_hi(tr.y)};
    const float uv[4] = {bf_lo(ur.x), bf_hi(ur.x), bf_lo(ur.y), bf_hi(ur.y)};
    #pragma unroll
    for (int a = 0; a < 4; ++a) {
      #pragma unroll
      for (int b = 0; b < 4; ++b) {
        acc[a][b] = fmaf(fabsf(tv[a] + uv[b]), w, acc[a][b]);
      }
    }
  }

  float* po = pz + (size_t)blockIdx.z * ((size_t)LL * LL);
  #pragma unroll
  for (int a = 0; a < 4; ++a) {
    const float Ai = As[4 * ty + a];
    float4 v;
    v.x = acc[a][0] + Ai + Bs[4 * tx + 0];
    v.y = acc[a][1] + Ai + Bs[4 * tx + 1];
    v.z = acc[a][2] + Ai + Bs[4 * tx + 2];
    v.w = acc[a][3] + Ai + Bs[4 * tx + 3];
    *(float4*)(po + (size_t)(i0 + 4 * ty + a) * LL + j0 + 4 * tx) = v;
  }
}

// ---------------------------------------------------------------------------
// Kernel 4 (R11-proven): out = sigmoid(0.25*(Q + Q^T) + b2), Q = pz0+pz1.
// 64x64 tiles, grid (16,16), 1024 thr, LDS transpose.
// ---------------------------------------------------------------------------
__global__ __launch_bounds__(1024) void sp_symsig(
    const float* __restrict__ pz, const float* __restrict__ b2,
    float* __restrict__ out) {
  __shared__ float B[64][65];
  const int i0 = blockIdx.y * 64;
  const int j0 = blockIdx.x * 64;
  const int r  = threadIdx.x >> 4;   // 0..63
  const int g  = threadIdx.x & 15;   // 0..15
  const size_t L2 = (size_t)LL * LL;

  const float* pm = pz + (size_t)(j0 + r) * LL + i0 + 4 * g;
  const float4 m0 = *(const float4*)(pm);
  const float4 m1 = *(const float4*)(pm + L2);
  B[r][4 * g + 0] = m0.x + m1.x;
  B[r][4 * g + 1] = m0.y + m1.y;
  B[r][4 * g + 2] = m0.z + m1.z;
  B[r][4 * g + 3] = m0.w + m1.w;
  __syncthreads();

  const float* pd = pz + (size_t)(i0 + r) * LL + j0 + 4 * g;
  const float4 d0 = *(const float4*)(pd);
  const float4 d1 = *(const float4*)(pd + L2);
  const float bb = b2[0];
  float4 o;
  float x;
  x = 0.25f * (d0.x + d1.x + B[4 * g + 0][r]) + bb; o.x = 1.f / (1.f + expf(-x));
  x = 0.25f * (d0.y + d1.y + B[4 * g + 1][r]) + bb; o.y = 1.f / (1.f + expf(-x));
  x = 0.25f * (d0.z + d1.z + B[4 * g + 2][r]) + bb; o.z = 1.f / (1.f + expf(-x));
  x = 0.25f * (d0.w + d1.w + B[4 * g + 3][r]) + bb; o.w = 1.f / (1.f + expf(-x));
  *(float4*)(out + (size_t)(i0 + r) * LL + j0 + 4 * g) = o;
}

// ---------------------------------------------------------------------------
extern "C" void kernel_launch(void* const* d_in, const int* in_sizes, int n_in,
                              void* d_out, int out_size, void* d_ws, size_t ws_size,
                              hipStream_t stream) {
  const float* S  = (const float*)d_in[0];   // [L, D]
  const float* W1 = (const float*)d_in[1];   // [H, 2D]
  const float* b1 = (const float*)d_in[2];   // [H]
  const float* W2 = (const float*)d_in[3];   // [1, H]
  const float* b2 = (const float*)d_in[4];   // [1]
  float* out = (float*)d_out;

  float* ws = (float*)d_ws;
  float* pC = ws;                            // [4][512][1024] f32
  ushort* O = (ushort*)(ws + 4 * 512 * LL);  // [512][1024] bf16
  float* pz = ws + 4 * 512 * LL + 262144;    // [2][1024][1024] f32

  hipLaunchKernelGGL(sp_gemm, dim3(8, 8, 4), dim3(512), 0, stream,
                     S, W1, pC);
  hipLaunchKernelGGL(sp_reduce, dim3(512), dim3(256), 0, stream,
                     pC, b1, O);
  hipLaunchKernelGGL(sp_pairwise, dim3(16, 16, 2), dim3(256), 0, stream,
                     O, W2, pz);
  hipLaunchKernelGGL(sp_symsig, dim3(16, 16), dim3(1024), 0, stream,
                     pz, b2, out);
}

// Round 16
// 46.076 us; speedup vs baseline: 1.5138x; 1.0876x over previous
//
#include <hip/hip_runtime.h>
#include <hip/hip_bf16.h>
#include <math.h>

#define LL 1024
#define DD 512
#define HH 256

// ws layout (floats):
//   pC : [4][512][1024] f32 @ 0         gemm K-partials (n = mat*256+h) (8 MB)
//   O  : [512][1024] bf16  @ 2097152    rows 0:256 = t(+b1), 256:512 = u (1 MB)
//   pz : [2][1024][1024] f32 @ 2359296  pairwise h-half partials        (8 MB)

__device__ __forceinline__ ushort f2bf(float f) {
  __hip_bfloat16 h = __float2bfloat16(f);
  return *reinterpret_cast<ushort*>(&h);
}
__device__ __forceinline__ float bfu(ushort u) {
  return __uint_as_float(((unsigned int)u) << 16);
}

// ---------------------------------------------------------------------------
// Kernel 1 (R11-proven, verbatim): GEMM partials. Tile 128i x 64n x 128k,
// 512 thr, 4i x 4n per thread, grid (8,8,4)=256. Dbuf BK=32.
// ---------------------------------------------------------------------------
__global__ __launch_bounds__(512) void sp_gemm(
    const float* __restrict__ S, const float* __restrict__ W1,
    float* __restrict__ pC) {
  __shared__ float Sl[2][128][36];   // 36.9 KB
  __shared__ float Wl[2][64][36];    // 18.4 KB

  const int tid = threadIdx.x;
  const int tx  = tid & 15;
  const int ty  = tid >> 4;
  const int i0  = blockIdx.x * 128;
  const int n0  = blockIdx.y * 64;
  const int kz  = blockIdx.z * 128;

  const int srow = tid >> 3;
  const int ssl  = tid & 7;
  const int wn   = n0 + srow;
  const float* s0 = S + (size_t)(i0 + srow) * DD + kz + 4 * ssl;
  const float* s1 = S + (size_t)(i0 + 64 + srow) * DD + kz + 4 * ssl;
  const float* w0 = W1 + (size_t)(wn & 255) * (2 * DD) + (wn >> 8) * DD + kz + 4 * ssl;

  float4 sA, sB, wA;
  auto ld = [&](int c) {
    sA = *(const float4*)(s0 + 32 * c);
    sB = *(const float4*)(s1 + 32 * c);
    wA = *(const float4*)(w0 + 32 * c);
  };
  auto st = [&](int b) {
    *(float4*)&Sl[b][srow][4 * ssl]      = sA;
    *(float4*)&Sl[b][64 + srow][4 * ssl] = sB;
    *(float4*)&Wl[b][srow][4 * ssl]      = wA;
  };

  float acc[4][4] = {{0.f}};

  ld(0); st(0); __syncthreads();

  for (int c = 0; c < 4; ++c) {
    const int cur = c & 1;
    if (c < 3) ld(c + 1);
    #pragma unroll 2
    for (int k4 = 0; k4 < 8; ++k4) {
      float4 wf[4], sf[4];
      #pragma unroll
      for (int b = 0; b < 4; ++b) wf[b] = *(const float4*)&Wl[cur][tx + 16 * b][4 * k4];
      #pragma unroll
      for (int a = 0; a < 4; ++a) sf[a] = *(const float4*)&Sl[cur][4 * ty + a][4 * k4];
      #pragma unroll
      for (int a = 0; a < 4; ++a) {
        #pragma unroll
        for (int b = 0; b < 4; ++b) {
          acc[a][b] += sf[a].x * wf[b].x + sf[a].y * wf[b].y +
                       sf[a].z * wf[b].z + sf[a].w * wf[b].w;
        }
      }
    }
    if (c < 3) st(cur ^ 1);
    __syncthreads();
  }

  float* base = pC + (size_t)blockIdx.z * (512 * LL);
  #pragma unroll
  for (int b = 0; b < 4; ++b) {
    const int n = n0 + tx + 16 * b;
    *(float4*)(base + (size_t)n * LL + i0 + 4 * ty) =
        make_float4(acc[0][b], acc[1][b], acc[2][b], acc[3][b]);
  }
}

// ---------------------------------------------------------------------------
// Kernel 2 (R14-proven): reduce 4 K-partials + fold b1 -> O bf16 [512][1024].
// grid 512 x 256 thr. ~2 us.
// ---------------------------------------------------------------------------
__global__ __launch_bounds__(256) void sp_reduce(
    const float* __restrict__ pC, const float* __restrict__ b1,
    ushort* __restrict__ O) {
  const int m = blockIdx.x * 256 + threadIdx.x;   // 0..131071 f4-groups
  const int n = m >> 8;
  const int NW = 512 * 256;                       // f4 per z-partial
  const float4* p = (const float4*)pC + m;
  float4 a  = p[0];
  const float4 v1 = p[NW], v2 = p[2 * NW], v3 = p[3 * NW];
  a.x += v1.x + v2.x + v3.x;
  a.y += v1.y + v2.y + v3.y;
  a.z += v1.z + v2.z + v3.z;
  a.w += v1.w + v2.w + v3.w;
  if (n < 256) {
    const float bb = b1[n];
    a.x += bb; a.y += bb; a.z += bb; a.w += bb;
  }
  ushort4 o;
  o.x = f2bf(a.x); o.y = f2bf(a.y); o.z = f2bf(a.z); o.w = f2bf(a.w);
  *(ushort4*)(O + 4 * (size_t)m) = o;
}

// ---------------------------------------------------------------------------
// Kernel 3 (R11's pairwise, ONLY the staging source changed: reads the
// 1 MB bf16 O instead of the 8 MB pC; fp32 LDS panels and inner loop
// byte-identical to R11). Block z covers h in [128z, 128z+128):
//   pz[z](i,j) = A_z(i) + B_z(j) + sum_h |t_i+u_j| * w2_h
// 512 thr, tile 64x64, 2i x 4j per thread. LDS 74 KB -> 2 blocks/CU
// = 16 waves/CU = 4 waves/SIMD. grid (16,16,2)=512.
// ---------------------------------------------------------------------------
__global__ __launch_bounds__(512) void sp_pairwise(
    const ushort* __restrict__ O, const float* __restrict__ W2,
    float* __restrict__ pz) {
  __shared__ float Tl[128][72];   // 36.9 KB
  __shared__ float Ul[128][72];   // 36.9 KB
  __shared__ float PR[4][128];
  __shared__ float As[64], Bs[64];

  const int tid = threadIdx.x;
  const int tx  = tid & 15;       // j = j0 + 4tx + b
  const int ty  = tid >> 4;       // i = i0 + 2ty + a, ty 0..31
  const int j0  = blockIdx.x * 64;
  const int i0  = blockIdx.y * 64;
  const int hz  = blockIdx.z * 128;

  // stage: bf16 O -> fp32 panels (ushort4 loads, convert, f4-equivalent LDS writes)
  #pragma unroll
  for (int q = 0; q < 4; ++q) {
    const int m = q * 512 + tid;           // 0..2047
    const int hh = m >> 4;                 // 0..127
    const int g4 = (m & 15) * 4;
    const ushort4 tv = *(const ushort4*)(O + (size_t)(hz + hh) * LL + i0 + g4);
    const ushort4 uv = *(const ushort4*)(O + (size_t)(HH + hz + hh) * LL + j0 + g4);
    *(float4*)&Tl[hh][g4] = make_float4(bfu(tv.x), bfu(tv.y), bfu(tv.z), bfu(tv.w));
    *(float4*)&Ul[hh][g4] = make_float4(bfu(uv.x), bfu(uv.y), bfu(uv.z), bfu(uv.w));
  }
  __syncthreads();

  // rank-1 prologue over this h-half: 128 cols x 4 h-slices of 32 (R11 verbatim)
  {
    const int x = tid & 127, hs = tid >> 7;    // hs 0..3
    const float* pan = (x < 64) ? &Tl[0][x] : &Ul[0][x - 64];
    float p = 0.f;
    #pragma unroll 8
    for (int n = 0; n < 32; ++n) {
      const int hh = hs * 32 + n;
      p = fmaf(pan[hh * 72], W2[hz + hh], p);
    }
    PR[hs][x] = p;
  }
  __syncthreads();
  if (tid < 128) {
    const float s = PR[0][tid] + PR[1][tid] + PR[2][tid] + PR[3][tid];
    if (tid < 64) As[tid] = s; else Bs[tid - 64] = s;
  }
  __syncthreads();

  float a0[4] = {0.f, 0.f, 0.f, 0.f};
  float a1[4] = {0.f, 0.f, 0.f, 0.f};

  #pragma unroll 4
  for (int hh = 0; hh < 128; ++hh) {
    const float2 tv = *(const float2*)&Tl[hh][2 * ty];
    const float4 uv = *(const float4*)&Ul[hh][4 * tx];
    const float w = W2[hz + hh];
    a0[0] = fmaf(fabsf(tv.x + uv.x), w, a0[0]);
    a0[1] = fmaf(fabsf(tv.x + uv.y), w, a0[1]);
    a0[2] = fmaf(fabsf(tv.x + uv.z), w, a0[2]);
    a0[3] = fmaf(fabsf(tv.x + uv.w), w, a0[3]);
    a1[0] = fmaf(fabsf(tv.y + uv.x), w, a1[0]);
    a1[1] = fmaf(fabsf(tv.y + uv.y), w, a1[1]);
    a1[2] = fmaf(fabsf(tv.y + uv.z), w, a1[2]);
    a1[3] = fmaf(fabsf(tv.y + uv.w), w, a1[3]);
  }

  const float A0 = As[2 * ty], A1 = As[2 * ty + 1];
  const float B0 = Bs[4 * tx], B1 = Bs[4 * tx + 1];
  const float B2 = Bs[4 * tx + 2], B3 = Bs[4 * tx + 3];
  float* po = pz + (size_t)blockIdx.z * ((size_t)LL * LL)
                 + (size_t)(i0 + 2 * ty) * LL + j0 + 4 * tx;
  *(float4*)po = make_float4(a0[0] + A0 + B0, a0[1] + A0 + B1,
                             a0[2] + A0 + B2, a0[3] + A0 + B3);
  *(float4*)(po + LL) = make_float4(a1[0] + A1 + B0, a1[1] + A1 + B1,
                                    a1[2] + A1 + B2, a1[3] + A1 + B3);
}

// ---------------------------------------------------------------------------
// Kernel 4 (R11-proven): out = sigmoid(0.25*(Q + Q^T) + b2), Q = pz0+pz1.
// 64x64 tiles, grid (16,16), 1024 thr, LDS transpose.
// ---------------------------------------------------------------------------
__global__ __launch_bounds__(1024) void sp_symsig(
    const float* __restrict__ pz, const float* __restrict__ b2,
    float* __restrict__ out) {
  __shared__ float B[64][65];
  const int i0 = blockIdx.y * 64;
  const int j0 = blockIdx.x * 64;
  const int r  = threadIdx.x >> 4;   // 0..63
  const int g  = threadIdx.x & 15;   // 0..15
  const size_t L2 = (size_t)LL * LL;

  const float* pm = pz + (size_t)(j0 + r) * LL + i0 + 4 * g;
  const float4 m0 = *(const float4*)(pm);
  const float4 m1 = *(const float4*)(pm + L2);
  B[r][4 * g + 0] = m0.x + m1.x;
  B[r][4 * g + 1] = m0.y + m1.y;
  B[r][4 * g + 2] = m0.z + m1.z;
  B[r][4 * g + 3] = m0.w + m1.w;
  __syncthreads();

  const float* pd = pz + (size_t)(i0 + r) * LL + j0 + 4 * g;
  const float4 d0 = *(const float4*)(pd);
  const float4 d1 = *(const float4*)(pd + L2);
  const float bb = b2[0];
  float4 o;
  float x;
  x = 0.25f * (d0.x + d1.x + B[4 * g + 0][r]) + bb; o.x = 1.f / (1.f + expf(-x));
  x = 0.25f * (d0.y + d1.y + B[4 * g + 1][r]) + bb; o.y = 1.f / (1.f + expf(-x));
  x = 0.25f * (d0.z + d1.z + B[4 * g + 2][r]) + bb; o.z = 1.f / (1.f + expf(-x));
  x = 0.25f * (d0.w + d1.w + B[4 * g + 3][r]) + bb; o.w = 1.f / (1.f + expf(-x));
  *(float4*)(out + (size_t)(i0 + r) * LL + j0 + 4 * g) = o;
}

// ---------------------------------------------------------------------------
extern "C" void kernel_launch(void* const* d_in, const int* in_sizes, int n_in,
                              void* d_out, int out_size, void* d_ws, size_t ws_size,
                              hipStream_t stream) {
  const float* S  = (const float*)d_in[0];   // [L, D]
  const float* W1 = (const float*)d_in[1];   // [H, 2D]
  const float* b1 = (const float*)d_in[2];   // [H]
  const float* W2 = (const float*)d_in[3];   // [1, H]
  const float* b2 = (const float*)d_in[4];   // [1]
  float* out = (float*)d_out;

  float* ws = (float*)d_ws;
  float* pC = ws;                            // [4][512][1024] f32
  ushort* O = (ushort*)(ws + 4 * 512 * LL);  // [512][1024] bf16
  float* pz = ws + 4 * 512 * LL + 262144;    // [2][1024][1024] f32

  hipLaunchKernelGGL(sp_gemm, dim3(8, 8, 4), dim3(512), 0, stream,
                     S, W1, pC);
  hipLaunchKernelGGL(sp_reduce, dim3(512), dim3(256), 0, stream,
                     pC, b1, O);
  hipLaunchKernelGGL(sp_pairwise, dim3(16, 16, 2), dim3(512), 0, stream,
                     O, W2, pz);
  hipLaunchKernelGGL(sp_symsig, dim3(16, 16), dim3(1024), 0, stream,
                     pz, b2, out);
}